// Round 14
// baseline (351.208 us; speedup 1.0000x reference)
//
#include <hip/hip_runtime.h>

typedef float f32x4 __attribute__((ext_vector_type(4)));
typedef short bf16x8 __attribute__((ext_vector_type(8)));

// ---------- helpers ----------
__device__ __forceinline__ unsigned int pk2(float a, float b) {
    unsigned int ua = __float_as_uint(a); ua += 0x7FFFu + ((ua >> 16) & 1u);
    unsigned int ub = __float_as_uint(b); ub += 0x7FFFu + ((ub >> 16) & 1u);
    return __builtin_amdgcn_perm(ub, ua, 0x07060302u);
}
__device__ __forceinline__ unsigned short bf16_rne(float a) {
    unsigned int ua = __float_as_uint(a);
    ua += 0x7FFFu + ((ua >> 16) & 1u);
    return (unsigned short)(ua >> 16);
}
__device__ __forceinline__ float tanh_fast(float x) {
    float e = __expf(x + x);
    return 1.f - 2.f / (e + 1.f);
}
__device__ __forceinline__ f32x4 mfma16(bf16x8 a, bf16x8 b, f32x4 c) {
    return __builtin_amdgcn_mfma_f32_16x16x32_bf16(a, b, c, 0, 0, 0);
}
// async global->LDS, 16B per lane; LDS dest = wave base + lane*16
__device__ __forceinline__ void ald16(const void* g, void* l) {
    __builtin_amdgcn_global_load_lds(
        (const __attribute__((address_space(1))) unsigned int*)g,
        (__attribute__((address_space(3))) unsigned int*)l, 16, 0, 0);
}

// ---------- 1. prep (small): only what the GRU GEMM needs ----------
#define QS_WIH  786432
#define QS_WHH  1572864
#define QS_X1   1589248
#define QS_X2   1605632
#define NCVT_S  6272

__global__ __launch_bounds__(256) void k_prep_s(
    const float* __restrict__ Wih, const float* __restrict__ Whh,
    const float* __restrict__ memory, const float* __restrict__ context,
    const float* __restrict__ rnn_state,
    unsigned short* __restrict__ Wihb, unsigned short* __restrict__ Whhb,
    unsigned short* __restrict__ X1b, unsigned short* __restrict__ X2b)
{
    int q = blockIdx.x * 256 + threadIdx.x;
    if (q >= QS_X2) return;
    if (q < QS_WIH) {
        int i = q * 4;
        float4 v = *(const float4*)(Wih + i);
        uint2 u; u.x = pk2(v.x, v.y); u.y = pk2(v.z, v.w);
        *(uint2*)(Wihb + i) = u;
    } else if (q < QS_WHH) {
        int i = (q - QS_WIH) * 4;
        float4 v = *(const float4*)(Whh + i);
        uint2 u; u.x = pk2(v.x, v.y); u.y = pk2(v.z, v.w);
        *(uint2*)(Whhb + i) = u;
    } else if (q < QS_X1) {
        int i = (q - QS_WHH) * 4;
        int b = i >> 10, c = i & 1023;
        const float* s = (c < 512) ? (memory + b * 512 + c) : (context + b * 512 + (c - 512));
        float4 v = *(const float4*)s;
        uint2 u; u.x = pk2(v.x, v.y); u.y = pk2(v.z, v.w);
        *(uint2*)(X1b + i) = u;
    } else {
        int i = (q - QS_X1) * 4;
        float4 v = *(const float4*)(rnn_state + i);
        uint2 u; u.x = pk2(v.x, v.y); u.y = pk2(v.z, v.w);
        *(uint2*)(X2b + i) = u;
    }
}

// ---------- 2. GRU GEMM (96 blocks) + hidden prep work (blocks 96..1392) ----------
__global__ __launch_bounds__(256, 4) void k_gru_plus(
    const unsigned short* __restrict__ X1b, const unsigned short* __restrict__ X2b,
    const unsigned short* __restrict__ Wihb, const unsigned short* __restrict__ Whhb,
    float* __restrict__ Cgru,
    const float* __restrict__ qw, const float* __restrict__ aw,
    const float* __restrict__ lw, const float* __restrict__ ab,
    const float* __restrict__ lb, const float* __restrict__ atten,
    const float* __restrict__ convw,
    unsigned short* __restrict__ qwb, unsigned short* __restrict__ Bbig,
    float* __restrict__ ebias, unsigned short* __restrict__ Lconv)
{
    __shared__ __align__(16) unsigned short As[64 * 32];
    __shared__ __align__(16) unsigned short Bs[128 * 32];
    __shared__ float att_s[2 * 160];
    __shared__ float cw_s[1984];
    const int tid = threadIdx.x;

    if (blockIdx.x < 96) {
        const int nb = blockIdx.x % 48;
        const int ks = blockIdx.x / 48;
        const int nBase = nb * 128;
        const bool use2 = nBase >= 3072;
        const unsigned short* A = use2 ? X2b : X1b;
        const unsigned short* B = use2 ? Whhb : Wihb;
        const int brow0 = nBase - (use2 ? 3072 : 0);
        const int lane = tid & 63, w = tid >> 6;
        const int c = lane & 15, qd = lane >> 4;
        const int lr = lane >> 2;
        const int swzl = ((lane & 3) ^ ((lr >> 1) & 3)) * 8;

        const f32x4 fz = {0.f, 0.f, 0.f, 0.f};
        f32x4 acc[4][2];
#pragma unroll
        for (int i = 0; i < 4; ++i) { acc[i][0] = fz; acc[i][1] = fz; }

        const int k0b = ks * 512;
        for (int kc = 0; kc < 16; ++kc) {
            const int k0 = k0b + kc * 32;
            ald16(A + (size_t)(w * 16 + lr) * 1024 + k0 + swzl, &As[w * 512]);
            ald16(B + (size_t)(brow0 + w * 16 + lr) * 1024 + k0 + swzl, &Bs[w * 512]);
            ald16(B + (size_t)(brow0 + 64 + w * 16 + lr) * 1024 + k0 + swzl, &Bs[2048 + w * 512]);
            __syncthreads();
            const int rdoff = (qd ^ ((c >> 1) & 3)) * 8;
            bf16x8 af[4];
#pragma unroll
            for (int i = 0; i < 4; ++i) af[i] = *(const bf16x8*)&As[(i * 16 + c) * 32 + rdoff];
#pragma unroll
            for (int j = 0; j < 2; ++j) {
                bf16x8 bj = *(const bf16x8*)&Bs[(w * 32 + j * 16 + c) * 32 + rdoff];
#pragma unroll
                for (int i = 0; i < 4; ++i) acc[i][j] = mfma16(af[i], bj, acc[i][j]);
            }
            __syncthreads();
        }
        float* Cp = Cgru + (size_t)ks * 64 * 6144;
#pragma unroll
        for (int i = 0; i < 4; ++i)
#pragma unroll
            for (int r = 0; r < 4; ++r) {
                int row = i * 16 + qd * 4 + r;
#pragma unroll
                for (int j = 0; j < 2; ++j) {
                    int col = nBase + w * 32 + j * 16 + c;
                    Cp[row * 6144 + col] = acc[i][j][r];
                }
            }
        return;
    }
    const int e = blockIdx.x - 96;
    if (e < 512) {                       // qwb convert (131072 quads)
        int q = e * 256 + tid;
        int i = q * 4;
        float4 v = *(const float4*)(qw + i);
        uint2 u; u.x = pk2(v.x, v.y); u.y = pk2(v.z, v.w);
        *(uint2*)(qwb + i) = u;
    } else if (e < 768) {                // Bbig aw part (65536 quads)
        int q = (e - 512) * 256 + tid;
        int i = q * 4;
        int a = i >> 9, c = i & 511;
        float4 v = *(const float4*)(aw + a * 512 + c);
        uint2 u; u.x = pk2(v.x, v.y); u.y = pk2(v.z, v.w);
        *(uint2*)(Bbig + a * 544 + c) = u;
    } else if (e < 784) {                // Bbig lw part (4096 quads)
        int q = (e - 768) * 256 + tid;
        int i = q * 4;
        int a = i >> 5, c = i & 31;
        float4 v = *(const float4*)(lw + a * 32 + c);
        uint2 u; u.x = pk2(v.x, v.y); u.y = pk2(v.z, v.w);
        *(uint2*)(Bbig + a * 544 + 512 + c) = u;
    } else if (e == 784) {               // ebias (128 quads)
        if (tid < 128) {
            int i = tid * 4;
            float4 va = *(const float4*)(ab + i);
            float4 vb = *(const float4*)(lb + i);
            float4 r; r.x = va.x + vb.x; r.y = va.y + vb.y; r.z = va.z + vb.z; r.w = va.w + vb.w;
            *(float4*)(ebias + i) = r;
        }
    } else {                             // Lconv location conv (512 blocks)
        const int bid = e - 785;
        const int b = bid >> 3;
        const int tbase = (bid & 7) * 128;
        for (int i = tid; i < 320; i += 256) {
            int c = i / 160, j = i % 160;
            float v = 0.f;
            int pos = tbase - 15 + j;
            if (j < 158 && pos >= 0 && pos < 1024) v = atten[b * 2048 + c * 1024 + pos];
            att_s[c * 160 + j] = v;
        }
        for (int i = tid; i < 1984; i += 256) cw_s[i] = convw[i];
        __syncthreads();
        const int f = tid & 31, tq = tid >> 5;
        float acc2[16];
#pragma unroll
        for (int i = 0; i < 16; ++i) acc2[i] = 0.f;
        for (int c = 0; c < 2; ++c) {
            for (int k = 0; k < 31; ++k) {
                float w = cw_s[f * 62 + c * 31 + k];
                int base = c * 160 + tq * 16 + k;
#pragma unroll
                for (int ti = 0; ti < 16; ++ti) acc2[ti] += w * att_s[base + ti];
            }
        }
#pragma unroll
        for (int ti = 0; ti < 16; ++ti) {
            int t = tbase + tq * 16 + ti;
            Lconv[(b * 1024 + t) * 32 + f] = bf16_rne(acc2[ti]);
        }
    }
}

// ---------- 3. pq GEMM with FUSED gates ----------
__global__ __launch_bounds__(256, 4) void k_pqg(
    const float* __restrict__ Cg, const float* __restrict__ h0,
    const float* __restrict__ bih, const float* __restrict__ bhh,
    const unsigned short* __restrict__ qwb, float* __restrict__ outv,
    float* __restrict__ pqC)
{
    __shared__ __align__(16) unsigned short As4[4][64 * 32];   // 16 KB
    __shared__ __align__(16) unsigned short Bs[128 * 32];      //  8 KB
    const int tid = threadIdx.x;
    const int nb = blockIdx.x & 3;
    const int ks = blockIdx.x >> 2;

    // ---- gates for K-slice [ks*128, ks*128+128), all 64 b ----
#pragma unroll 4
    for (int r = 0; r < 32; ++r) {
        int idx = r * 256 + tid;
        int b = idx >> 7, hl = idx & 127;
        int h = ks * 128 + hl;
        const float* g0 = Cg + b * 6144;
        const float* g1 = Cg + 393216 + b * 6144;
        float ir = g0[h] + g1[h] + bih[h];
        float iz = g0[h + 1024] + g1[h + 1024] + bih[h + 1024];
        float inn = g0[h + 2048] + g1[h + 2048] + bih[h + 2048];
        float hr = g0[h + 3072] + g1[h + 3072] + bhh[h];
        float hz = g0[h + 4096] + g1[h + 4096] + bhh[h + 1024];
        float hn = g0[h + 5120] + g1[h + 5120] + bhh[h + 2048];
        float rg = 1.f / (1.f + __expf(-(ir + hr)));
        float z = 1.f / (1.f + __expf(-(iz + hz)));
        float n = tanh_fast(inn + rg * hn);
        float o = (1.f - z) * n + z * h0[b * 1024 + h];
        if (nb == 0) outv[b * 1024 + h] = o;
        int kcL = hl >> 5, j = hl & 31;
        int s = (j >> 3) ^ ((b >> 1) & 3);
        As4[kcL][b * 32 + s * 8 + (j & 7)] = bf16_rne(o);
    }
    __syncthreads();

    // ---- 4-iter GEMM: A from As4 (LDS-resident), B staged per iter ----
    const int lane = tid & 63, w = tid >> 6;
    const int c = lane & 15, qd = lane >> 4;
    const int lr = lane >> 2;
    const int swzl = ((lane & 3) ^ ((lr >> 1) & 3)) * 8;
    const int nBase = nb * 128;
    const f32x4 fz = {0.f, 0.f, 0.f, 0.f};
    f32x4 acc[4][2];
#pragma unroll
    for (int i = 0; i < 4; ++i) { acc[i][0] = fz; acc[i][1] = fz; }

    for (int kc = 0; kc < 4; ++kc) {
        const int k0 = ks * 128 + kc * 32;
        ald16(qwb + (size_t)(nBase + w * 16 + lr) * 1024 + k0 + swzl, &Bs[w * 512]);
        ald16(qwb + (size_t)(nBase + 64 + w * 16 + lr) * 1024 + k0 + swzl, &Bs[2048 + w * 512]);
        __syncthreads();
        const int rdoff = (qd ^ ((c >> 1) & 3)) * 8;
        bf16x8 af[4];
#pragma unroll
        for (int i = 0; i < 4; ++i) af[i] = *(const bf16x8*)&As4[kc][(i * 16 + c) * 32 + rdoff];
#pragma unroll
        for (int j = 0; j < 2; ++j) {
            bf16x8 bj = *(const bf16x8*)&Bs[(w * 32 + j * 16 + c) * 32 + rdoff];
#pragma unroll
            for (int i = 0; i < 4; ++i) acc[i][j] = mfma16(af[i], bj, acc[i][j]);
        }
        __syncthreads();
    }
    float* Cp = pqC + (size_t)ks * 32768;
#pragma unroll
    for (int i = 0; i < 4; ++i)
#pragma unroll
        for (int r = 0; r < 4; ++r) {
            int row = i * 16 + qd * 4 + r;
#pragma unroll
            for (int j = 0; j < 2; ++j) {
                int col = nBase + w * 32 + j * 16 + c;
                Cp[row * 512 + col] = acc[i][j][r];
            }
        }
}

// ---------- 4. energy GEMM M=128 + FUSED context partial ----------
// Per-CU delivery model (11-12 B/cyc/CU, confirmed R2/R6/R13): only Bbig
// shrinks with fewer blocks. M=128, 512 threads / 8 waves; wave (wm,wn) owns
// a 64x128 quadrant with the R2-exact acc[4][8] + 32-MFMA inner loop.
// ~244 unified regs (launch_bounds(512,2) caps at 256); LDS 84.5 KB ->
// 1 block/CU = 8 waves (same occupancy as before); per-CU bytes 3.24->2.15MB.
__global__ __launch_bounds__(512, 2) void k_attn(
    const float* __restrict__ annots, const unsigned short* __restrict__ Lconv,
    const unsigned short* __restrict__ Bbig, const float* __restrict__ pqP,
    const float* __restrict__ qb, const float* __restrict__ ebias,
    const float* __restrict__ vw, const int* __restrict__ mask,
    float* __restrict__ wsal, float* __restrict__ ctxP)
{
    __shared__ __align__(16) unsigned short As[2][128 * 32];   // 16 KB
    __shared__ __align__(16) unsigned short Bs[2][512 * 32];   // 64 KB
    __shared__ float red[8][64];                               //  2 KB
    __shared__ float sv[128];
    const int tid = threadIdx.x;
    const int btBase = blockIdx.x * 128;
    const int b = btBase >> 10;
    const int lane = tid & 63, w = tid >> 6;      // 8 waves
    const int wm = w >> 2, wn = w & 3;            // 64-row half, 128-col quarter
    const int c = lane & 15, qd = lane >> 4;
    const int lr = lane >> 2;
    const int swzl = ((lane & 3) ^ ((lr >> 1) & 3)) * 8;
    const int arow = tid >> 2, alc = tid & 3;     // A-convert: 128 rows x 4 thr
    const int apofs = (alc ^ ((arow >> 1) & 3)) * 8;

    const f32x4 fz = {0.f, 0.f, 0.f, 0.f};
    f32x4 acc[4][8];
#pragma unroll
    for (int i = 0; i < 4; ++i)
#pragma unroll
        for (int j = 0; j < 8; ++j) acc[i][j] = fz;

    const float* aP = annots + (size_t)(btBase + arow) * 512 + alc * 8;
    const unsigned short* bP = Bbig + (size_t)(w * 16 + lr) * 544 + swzl;

    // ---- prologue: stage B tile 0 (4 ald16/wave), convert A tile 0 ----
#pragma unroll
    for (int s = 0; s < 4; ++s)
        ald16(bP + (size_t)s * 128 * 544, &Bs[0][(s * 128 + w * 16) * 32]);
    {
        float4 v0 = *(const float4*)(aP);
        float4 v1 = *(const float4*)(aP + 4);
        uint4 u;
        u.x = pk2(v0.x, v0.y); u.y = pk2(v0.z, v0.w);
        u.z = pk2(v1.x, v1.y); u.w = pk2(v1.z, v1.w);
        *(uint4*)&As[0][arow * 32 + apofs] = u;
    }
    __syncthreads();

    for (int kc = 0; kc < 17; ++kc) {
        const int cur = kc & 1, nxt = cur ^ 1;
        float4 v0n, v1n;
        // ---- issue next tile's loads (latency hides under this tile's compute)
        if (kc < 16) {
            const int k1 = (kc + 1) * 32;
#pragma unroll
            for (int s = 0; s < 4; ++s)
                ald16(bP + (size_t)s * 128 * 544 + k1, &Bs[nxt][(s * 128 + w * 16) * 32]);
            if (kc < 15) {
                v0n = *(const float4*)(aP + k1);
                v1n = *(const float4*)(aP + k1 + 4);
            } else {
                ald16(Lconv + (size_t)(btBase + w * 16 + lr) * 32 + swzl, &As[nxt][w * 512]);
            }
        }
        // ---- compute current tile
        const int rdoff = (qd ^ ((c >> 1) & 3)) * 8;
        bf16x8 af[4];
#pragma unroll
        for (int i = 0; i < 4; ++i)
            af[i] = *(const bf16x8*)&As[cur][(wm * 64 + i * 16 + c) * 32 + rdoff];
        __builtin_amdgcn_s_setprio(1);
#pragma unroll
        for (int j = 0; j < 8; ++j) {
            bf16x8 bj = *(const bf16x8*)&Bs[cur][(wn * 128 + j * 16 + c) * 32 + rdoff];
#pragma unroll
            for (int i = 0; i < 4; ++i) acc[i][j] = mfma16(af[i], bj, acc[i][j]);
        }
        __builtin_amdgcn_s_setprio(0);
        // ---- write-late: convert prefetched annots into As[nxt], then ONE barrier
        if (kc < 16) {
            if (kc < 15) {
                uint4 u;
                u.x = pk2(v0n.x, v0n.y); u.y = pk2(v0n.z, v0n.w);
                u.z = pk2(v1n.x, v1n.y); u.w = pk2(v1n.z, v1n.w);
                *(uint4*)&As[nxt][arow * 32 + apofs] = u;
            }
            __syncthreads();
        }
    }
    // ---- epilogue 1: raw alignment + sig into LDS ----
    float pe[8], vv[8];
#pragma unroll
    for (int j = 0; j < 8; ++j) {
        int colg = wn * 128 + j * 16 + c;
        float s = qb[colg] + ebias[colg];
#pragma unroll
        for (int p = 0; p < 8; ++p) s += pqP[p * 32768 + b * 512 + colg];
        pe[j] = s;
        vv[j] = vw[colg];
    }
#pragma unroll
    for (int i = 0; i < 4; ++i)
#pragma unroll
        for (int r = 0; r < 4; ++r) {
            float p = 0.f;
#pragma unroll
            for (int j = 0; j < 8; ++j)
                p += vv[j] * tanh_fast(acc[i][j][r] + pe[j]);
            p += __shfl_xor(p, 1);
            p += __shfl_xor(p, 2);
            p += __shfl_xor(p, 4);
            p += __shfl_xor(p, 8);
            if (c == 0) red[w][i * 16 + qd * 4 + r] = p;
        }
    __syncthreads();
    if (tid < 128) {
        const int half = tid >> 6, row = tid & 63;
        float raw = red[half * 4 + 0][row] + red[half * 4 + 1][row]
                  + red[half * 4 + 2][row] + red[half * 4 + 3][row];
        wsal[btBase + tid] = raw;
        sv[tid] = (mask[btBase + tid] != 0) ? 1.f / (1.f + __expf(-raw)) : 0.f;
    }
    __syncthreads();
    // ---- epilogue 2: fused context partial (wave w: rows w*16..w*16+15) ----
    {
        float cacc[8];
#pragma unroll
        for (int k = 0; k < 8; ++k) cacc[k] = 0.f;
        const float* ar = annots + (size_t)(btBase + w * 16) * 512 + lane * 8;
#pragma unroll 4
        for (int r2 = 0; r2 < 16; ++r2) {
            float s = sv[w * 16 + r2];
            float4 va = *(const float4*)(ar + (size_t)r2 * 512);
            float4 vb = *(const float4*)(ar + (size_t)r2 * 512 + 4);
            cacc[0] += s * va.x; cacc[1] += s * va.y;
            cacc[2] += s * va.z; cacc[3] += s * va.w;
            cacc[4] += s * vb.x; cacc[5] += s * vb.y;
            cacc[6] += s * vb.z; cacc[7] += s * vb.w;
        }
        // reduce across 8 waves via LDS (As dead -> 4096-float scratch)
        float* cxf = (float*)&As[0][0];
#pragma unroll
        for (int k = 0; k < 8; ++k) cxf[w * 512 + lane * 8 + k] = cacc[k];
        __syncthreads();
        const int chunk = blockIdx.x & 7;
        float* cp = ctxP + ((size_t)chunk * 64 + b) * 512;
        float s8 = 0.f;
#pragma unroll
        for (int w2 = 0; w2 < 8; ++w2) s8 += cxf[w2 * 512 + tid];
        cp[tid] = s8;
    }
}

// ---------- 5. normalize: alignment out + context reduce (8 chunks) ----------
__global__ __launch_bounds__(256) void k_ctxB(
    const float* __restrict__ wsal, const int* __restrict__ mask,
    const float* __restrict__ ctxP, float* __restrict__ out)
{
    __shared__ float sv[1024];
    __shared__ float wsum[4];
    const int b = blockIdx.x;
    const int tid = threadIdx.x;
    float lsum = 0.f;
#pragma unroll
    for (int p = 0; p < 4; ++p) {
        int t = p * 256 + tid;
        int bt = b * 1024 + t;
        float raw = wsal[bt];
        float s = (mask[bt] != 0) ? 1.f / (1.f + __expf(-raw)) : 0.f;
        sv[t] = s;
        lsum += s;
    }
    for (int off = 32; off > 0; off >>= 1) lsum += __shfl_xor(lsum, off);
    if ((tid & 63) == 0) wsum[tid >> 6] = lsum;
    __syncthreads();
    const float tot = wsum[0] + wsum[1] + wsum[2] + wsum[3];
    const float inv = 1.f / tot;
#pragma unroll
    for (int p = 0; p < 4; ++p) {
        int t = p * 256 + tid;
        out[98304 + b * 1024 + t] = sv[t] * inv;
    }
#pragma unroll
    for (int h = 0; h < 2; ++h) {
        int d = h * 256 + tid;
        float csum = 0.f;
#pragma unroll
        for (int tc = 0; tc < 8; ++tc)
            csum += ctxP[((size_t)tc * 64 + b) * 512 + d];
        out[65536 + b * 512 + d] = csum * inv;
    }
}

extern "C" void kernel_launch(void* const* d_in, const int* in_sizes, int n_in,
                              void* d_out, int out_size, void* d_ws, size_t ws_size,
                              hipStream_t stream) {
    const float* memory    = (const float*)d_in[0];
    const float* context   = (const float*)d_in[1];
    const float* rnn_state = (const float*)d_in[2];
    const float* annots    = (const float*)d_in[3];
    const float* atten     = (const float*)d_in[4];
    const int*   mask      = (const int*)d_in[5];
    const float* W_ih   = (const float*)d_in[7];
    const float* W_hh   = (const float*)d_in[8];
    const float* b_ih   = (const float*)d_in[9];
    const float* b_hh   = (const float*)d_in[10];
    const float* conv_w = (const float*)d_in[11];
    const float* loc_w  = (const float*)d_in[12];
    const float* loc_b  = (const float*)d_in[13];
    const float* q_w    = (const float*)d_in[14];
    const float* q_b    = (const float*)d_in[15];
    const float* a_w    = (const float*)d_in[16];
    const float* a_b    = (const float*)d_in[17];
    const float* v_w    = (const float*)d_in[18];
    float* out = (float*)d_out;

    // Workspace layout — stays within the proven 21,923,840-byte footprint.
    char* w8 = (char*)d_ws;
    unsigned short* Lconv = (unsigned short*)(w8 + 0);         //  4,194,304
    unsigned short* Bbig  = (unsigned short*)(w8 + 4194304);   //    557,056
    unsigned short* Wihb  = (unsigned short*)(w8 + 4751360);   //  6,291,456 (dead after k_gru_plus)
    unsigned short* Whhb  = (unsigned short*)(w8 + 11042816);  //  6,291,456 (dead after k_gru_plus)
    unsigned short* qwb   = (unsigned short*)(w8 + 17334272);  //  1,048,576
    unsigned short* X1b   = (unsigned short*)(w8 + 18382848);  //    131,072
    unsigned short* X2b   = (unsigned short*)(w8 + 18513920);  //    131,072
    float*          Cgru  = (float*)(w8 + 18776064);           //  3,145,728 (dead after k_pqg)
    // Aliases (stream-ordered, all within footprint):
    //   pqP  (1MB, written by k_pqg)    -> Whhb slot (dead)
    //   ctxP (1MB, written by k_attn)   -> Wihb slot (dead)
    //   wsal (256KB, written by k_attn) -> Cgru tail (dead after k_pqg)
    float*          pqP   = (float*)(w8 + 11042816);
    float*          ctxP  = (float*)(w8 + 4751360);
    float*          wsal  = (float*)(w8 + 19824640);
    float*          ebias = (float*)(w8 + 21921792);           //      2,048

    k_prep_s<<<NCVT_S, 256, 0, stream>>>(W_ih, W_hh, memory, context, rnn_state,
                                         Wihb, Whhb, X1b, X2b);
    k_gru_plus<<<1393, 256, 0, stream>>>(X1b, X2b, Wihb, Whhb, Cgru,
                                         q_w, a_w, loc_w, a_b, loc_b, atten, conv_w,
                                         qwb, Bbig, ebias, Lconv);
    k_pqg<<<32, 256, 0, stream>>>(Cgru, rnn_state, b_ih, b_hh, qwb, out, pqP);
    // energy: M=128 per block, 512 blocks
    k_attn<<<512, 512, 0, stream>>>(annots, Lconv, Bbig, pqP, q_b, ebias, v_w, mask, wsal, ctxP);
    k_ctxB<<<64, 256, 0, stream>>>(wsal, mask, ctxP, out);
}

// Round 15
// 326.996 us; speedup vs baseline: 1.0740x; 1.0740x over previous
//
#include <hip/hip_runtime.h>

typedef float f32x4 __attribute__((ext_vector_type(4)));
typedef short bf16x8 __attribute__((ext_vector_type(8)));

// ---------- helpers ----------
__device__ __forceinline__ unsigned int pk2(float a, float b) {
    unsigned int ua = __float_as_uint(a); ua += 0x7FFFu + ((ua >> 16) & 1u);
    unsigned int ub = __float_as_uint(b); ub += 0x7FFFu + ((ub >> 16) & 1u);
    return __builtin_amdgcn_perm(ub, ua, 0x07060302u);
}
__device__ __forceinline__ unsigned short bf16_rne(float a) {
    unsigned int ua = __float_as_uint(a);
    ua += 0x7FFFu + ((ua >> 16) & 1u);
    return (unsigned short)(ua >> 16);
}
__device__ __forceinline__ float tanh_fast(float x) {
    float e = __expf(x + x);
    return 1.f - 2.f / (e + 1.f);
}
__device__ __forceinline__ f32x4 mfma16(bf16x8 a, bf16x8 b, f32x4 c) {
    return __builtin_amdgcn_mfma_f32_16x16x32_bf16(a, b, c, 0, 0, 0);
}
// async global->LDS, 16B per lane; LDS dest = wave base + lane*16
__device__ __forceinline__ void ald16(const void* g, void* l) {
    __builtin_amdgcn_global_load_lds(
        (const __attribute__((address_space(1))) unsigned int*)g,
        (__attribute__((address_space(3))) unsigned int*)l, 16, 0, 0);
}

// ---------- 1. prep: fp32->bf16 weight conversion + location conv ----------
#define Q_WIH   786432
#define Q_WHH   1572864
#define Q_QW    1703936
#define Q_X2    1720320
#define Q_X1    1736704
#define Q_BAW   1802240
#define Q_BLW   1806336
#define Q_EB    1806464
#define NCVT    7057

__global__ __launch_bounds__(256) void k_prep(
    const float* __restrict__ Wih, const float* __restrict__ Whh,
    const float* __restrict__ qw, const float* __restrict__ rnn_state,
    const float* __restrict__ memory, const float* __restrict__ context,
    const float* __restrict__ aw, const float* __restrict__ lw,
    const float* __restrict__ ab, const float* __restrict__ lb,
    const float* __restrict__ atten, const float* __restrict__ convw,
    unsigned short* __restrict__ Wihb, unsigned short* __restrict__ Whhb,
    unsigned short* __restrict__ qwb, unsigned short* __restrict__ X2b,
    unsigned short* __restrict__ X1b, unsigned short* __restrict__ Bbig,
    float* __restrict__ ebias, unsigned short* __restrict__ Lconv)
{
    __shared__ float att_s[2 * 160];
    __shared__ float cw_s[1984];
    const int tid = threadIdx.x;
    if (blockIdx.x < NCVT) {
        int q = blockIdx.x * 256 + tid;
        if (q >= Q_EB) return;
        if (q < Q_WIH) {
            int i = q * 4;
            float4 v = *(const float4*)(Wih + i);
            uint2 u; u.x = pk2(v.x, v.y); u.y = pk2(v.z, v.w);
            *(uint2*)(Wihb + i) = u;
        } else if (q < Q_WHH) {
            int i = (q - Q_WIH) * 4;
            float4 v = *(const float4*)(Whh + i);
            uint2 u; u.x = pk2(v.x, v.y); u.y = pk2(v.z, v.w);
            *(uint2*)(Whhb + i) = u;
        } else if (q < Q_QW) {
            int i = (q - Q_WHH) * 4;
            float4 v = *(const float4*)(qw + i);
            uint2 u; u.x = pk2(v.x, v.y); u.y = pk2(v.z, v.w);
            *(uint2*)(qwb + i) = u;
        } else if (q < Q_X2) {
            int i = (q - Q_QW) * 4;
            float4 v = *(const float4*)(rnn_state + i);
            uint2 u; u.x = pk2(v.x, v.y); u.y = pk2(v.z, v.w);
            *(uint2*)(X2b + i) = u;
        } else if (q < Q_X1) {
            int i = (q - Q_X2) * 4;
            int b = i >> 10, c = i & 1023;
            const float* s = (c < 512) ? (memory + b * 512 + c) : (context + b * 512 + (c - 512));
            float4 v = *(const float4*)s;
            uint2 u; u.x = pk2(v.x, v.y); u.y = pk2(v.z, v.w);
            *(uint2*)(X1b + i) = u;
        } else if (q < Q_BAW) {
            int i = (q - Q_X1) * 4;
            int a = i >> 9, c = i & 511;
            float4 v = *(const float4*)(aw + a * 512 + c);
            uint2 u; u.x = pk2(v.x, v.y); u.y = pk2(v.z, v.w);
            *(uint2*)(Bbig + a * 544 + c) = u;
        } else if (q < Q_BLW) {
            int i = (q - Q_BAW) * 4;
            int a = i >> 5, c = i & 31;
            float4 v = *(const float4*)(lw + a * 32 + c);
            uint2 u; u.x = pk2(v.x, v.y); u.y = pk2(v.z, v.w);
            *(uint2*)(Bbig + a * 544 + 512 + c) = u;
        } else {
            int i = (q - Q_BLW) * 4;
            float4 va = *(const float4*)(ab + i);
            float4 vb = *(const float4*)(lb + i);
            float4 r; r.x = va.x + vb.x; r.y = va.y + vb.y; r.z = va.z + vb.z; r.w = va.w + vb.w;
            *(float4*)(ebias + i) = r;
        }
    } else {
        const int bid = blockIdx.x - NCVT;
        const int b = bid >> 3;
        const int tbase = (bid & 7) * 128;
        for (int i = tid; i < 320; i += 256) {
            int c = i / 160, j = i % 160;
            float v = 0.f;
            int pos = tbase - 15 + j;
            if (j < 158 && pos >= 0 && pos < 1024) v = atten[b * 2048 + c * 1024 + pos];
            att_s[c * 160 + j] = v;
        }
        for (int i = tid; i < 1984; i += 256) cw_s[i] = convw[i];
        __syncthreads();
        const int f = tid & 31, tq = tid >> 5;
        float acc[16];
#pragma unroll
        for (int i = 0; i < 16; ++i) acc[i] = 0.f;
        for (int c = 0; c < 2; ++c) {
            for (int k = 0; k < 31; ++k) {
                float w = cw_s[f * 62 + c * 31 + k];
                int base = c * 160 + tq * 16 + k;
#pragma unroll
                for (int ti = 0; ti < 16; ++ti) acc[ti] += w * att_s[base + ti];
            }
        }
#pragma unroll
        for (int ti = 0; ti < 16; ++ti) {
            int t = tbase + tq * 16 + ti;
            Lconv[(b * 1024 + t) * 32 + f] = bf16_rne(acc[ti]);
        }
    }
}

// ---------- 2. M=64 K-split GEMM, N-tile 128: C[ks][64][N] partial = A @ B^T ----------
__global__ __launch_bounds__(256, 4) void k_gemm_ks(
    const unsigned short* __restrict__ A1, const unsigned short* __restrict__ A2,
    const unsigned short* __restrict__ B1, const unsigned short* __restrict__ B2,
    float* __restrict__ C, int N, int nTiles, int n_split, int K, int Klen)
{
    __shared__ __align__(16) unsigned short As[64 * 32];
    __shared__ __align__(16) unsigned short Bs[128 * 32];
    const int tid = threadIdx.x;
    const int nb = blockIdx.x % nTiles;
    const int ks = blockIdx.x / nTiles;
    const int nBase = nb * 128;
    const bool use2 = nBase >= n_split;
    const unsigned short* A = use2 ? A2 : A1;
    const unsigned short* B = use2 ? B2 : B1;
    const int brow0 = nBase - (use2 ? n_split : 0);
    const int lane = tid & 63, w = tid >> 6;
    const int c = lane & 15, qd = lane >> 4;
    const int lr = lane >> 2;
    const int swzl = ((lane & 3) ^ ((lr >> 1) & 3)) * 8;

    const f32x4 fz = {0.f, 0.f, 0.f, 0.f};
    f32x4 acc[4][2];
#pragma unroll
    for (int i = 0; i < 4; ++i) { acc[i][0] = fz; acc[i][1] = fz; }

    const int k0b = ks * Klen;
    const int nkc = Klen >> 5;
    for (int kc = 0; kc < nkc; ++kc) {
        const int k0 = k0b + kc * 32;
        ald16(A + (size_t)(w * 16 + lr) * K + k0 + swzl, &As[w * 512]);
        ald16(B + (size_t)(brow0 + w * 16 + lr) * K + k0 + swzl, &Bs[w * 512]);
        ald16(B + (size_t)(brow0 + 64 + w * 16 + lr) * K + k0 + swzl, &Bs[2048 + w * 512]);
        __syncthreads();
        const int rdoff = (qd ^ ((c >> 1) & 3)) * 8;
        bf16x8 af[4];
#pragma unroll
        for (int i = 0; i < 4; ++i) af[i] = *(const bf16x8*)&As[(i * 16 + c) * 32 + rdoff];
#pragma unroll
        for (int j = 0; j < 2; ++j) {
            bf16x8 bj = *(const bf16x8*)&Bs[(w * 32 + j * 16 + c) * 32 + rdoff];
#pragma unroll
            for (int i = 0; i < 4; ++i) acc[i][j] = mfma16(af[i], bj, acc[i][j]);
        }
        __syncthreads();
    }
    float* Cp = C + (size_t)ks * 64 * N;
#pragma unroll
    for (int i = 0; i < 4; ++i)
#pragma unroll
        for (int r = 0; r < 4; ++r) {
            int row = i * 16 + qd * 4 + r;
#pragma unroll
            for (int j = 0; j < 2; ++j) {
                int col = nBase + w * 32 + j * 16 + c;
                Cp[row * N + col] = acc[i][j][r];
            }
        }
}

// ---------- 3. GRU gates (sums K-split partials, adds biases) ----------
__global__ __launch_bounds__(256) void k_gates(
    const float* __restrict__ Cg, const float* __restrict__ h0,
    const float* __restrict__ bih, const float* __restrict__ bhh,
    float* __restrict__ outv, unsigned short* __restrict__ X3b)
{
    int idx = blockIdx.x * 256 + threadIdx.x;
    int b = idx >> 10, h = idx & 1023;
    const float* g0 = Cg + b * 6144;
    const float* g1 = Cg + 393216 + b * 6144;
    float ir = g0[h] + g1[h] + bih[h];
    float iz = g0[h + 1024] + g1[h + 1024] + bih[h + 1024];
    float inn = g0[h + 2048] + g1[h + 2048] + bih[h + 2048];
    float hr = g0[h + 3072] + g1[h + 3072] + bhh[h];
    float hz = g0[h + 4096] + g1[h + 4096] + bhh[h + 1024];
    float hn = g0[h + 5120] + g1[h + 5120] + bhh[h + 2048];
    float r = 1.f / (1.f + __expf(-(ir + hr)));
    float z = 1.f / (1.f + __expf(-(iz + hz)));
    float n = tanh_fast(inn + r * hn);
    float o = (1.f - z) * n + z * h0[idx];
    outv[idx] = o;
    X3b[idx] = bf16_rne(o);
}

// ---------- 4. energy GEMM + FUSED context partial ----------
// Main loop = R2-exact (measured 99us). Epilogue: this block owns the 64
// annot rows whose sig-weights it just computed, so it also produces the
// unnormalized context partial sum_t sig(raw[t])*annots[t,:] by re-reading
// its own 131KB of annots (L2/L3-served) row-major coalesced.
__global__ __launch_bounds__(256, 2) void k_attn(
    const float* __restrict__ annots, const unsigned short* __restrict__ Lconv,
    const unsigned short* __restrict__ Bbig, const float* __restrict__ pqP,
    const float* __restrict__ qb, const float* __restrict__ ebias,
    const float* __restrict__ vw, const int* __restrict__ mask,
    float* __restrict__ wsal, float* __restrict__ ctxP)
{
    __shared__ __align__(16) unsigned short As[2][64 * 32];    //  8 KB
    __shared__ __align__(16) unsigned short Bs[2][512 * 32];   // 64 KB
    __shared__ float red[4][64];
    __shared__ float sv[64];
    const int tid = threadIdx.x;
    const int btBase = blockIdx.x * 64;
    const int b = btBase >> 10;
    const int lane = tid & 63, w = tid >> 6;
    const int c = lane & 15, qd = lane >> 4;
    const int lr = lane >> 2;
    const int swzl = ((lane & 3) ^ ((lr >> 1) & 3)) * 8;
    const int arow = tid >> 2, alc = tid & 3;
    const int apofs = (alc ^ ((arow >> 1) & 3)) * 8;

    const f32x4 fz = {0.f, 0.f, 0.f, 0.f};
    f32x4 acc[4][8];
#pragma unroll
    for (int i = 0; i < 4; ++i)
#pragma unroll
        for (int j = 0; j < 8; ++j) acc[i][j] = fz;

    const float* aP = annots + (size_t)(btBase + arow) * 512 + alc * 8;
    const unsigned short* bP = Bbig + (size_t)(w * 16 + lr) * 544 + swzl;

#pragma unroll
    for (int s = 0; s < 8; ++s)
        ald16(bP + (size_t)s * 64 * 544, &Bs[0][s * 2048 + w * 512]);
    {
        float4 v0 = *(const float4*)(aP);
        float4 v1 = *(const float4*)(aP + 4);
        uint4 u;
        u.x = pk2(v0.x, v0.y); u.y = pk2(v0.z, v0.w);
        u.z = pk2(v1.x, v1.y); u.w = pk2(v1.z, v1.w);
        *(uint4*)&As[0][arow * 32 + apofs] = u;
    }
    __syncthreads();

    for (int kc = 0; kc < 17; ++kc) {
        const int cur = kc & 1, nxt = cur ^ 1;
        float4 v0n, v1n;
        if (kc < 16) {
            const int k1 = (kc + 1) * 32;
#pragma unroll
            for (int s = 0; s < 8; ++s)
                ald16(bP + (size_t)s * 64 * 544 + k1, &Bs[nxt][s * 2048 + w * 512]);
            if (kc < 15) {
                v0n = *(const float4*)(aP + k1);
                v1n = *(const float4*)(aP + k1 + 4);
            } else {
                ald16(Lconv + (size_t)(btBase + w * 16 + lr) * 32 + swzl, &As[nxt][w * 512]);
            }
        }
        const int rdoff = (qd ^ ((c >> 1) & 3)) * 8;
        bf16x8 af[4];
#pragma unroll
        for (int i = 0; i < 4; ++i) af[i] = *(const bf16x8*)&As[cur][(i * 16 + c) * 32 + rdoff];
        __builtin_amdgcn_s_setprio(1);
#pragma unroll
        for (int j = 0; j < 8; ++j) {
            bf16x8 bj = *(const bf16x8*)&Bs[cur][(w * 128 + j * 16 + c) * 32 + rdoff];
#pragma unroll
            for (int i = 0; i < 4; ++i) acc[i][j] = mfma16(af[i], bj, acc[i][j]);
        }
        __builtin_amdgcn_s_setprio(0);
        if (kc < 16) {
            if (kc < 15) {
                uint4 u;
                u.x = pk2(v0n.x, v0n.y); u.y = pk2(v0n.z, v0n.w);
                u.z = pk2(v1n.x, v1n.y); u.w = pk2(v1n.z, v1n.w);
                *(uint4*)&As[nxt][arow * 32 + apofs] = u;
            }
            __syncthreads();
        }
    }
    // ---- epilogue 1: raw alignment + sig into LDS ----
    float pe[8], vv[8];
#pragma unroll
    for (int j = 0; j < 8; ++j) {
        int colg = w * 128 + j * 16 + c;
        float s = qb[colg] + ebias[colg];
#pragma unroll
        for (int p = 0; p < 8; ++p) s += pqP[p * 32768 + b * 512 + colg];
        pe[j] = s;
        vv[j] = vw[colg];
    }
#pragma unroll
    for (int i = 0; i < 4; ++i)
#pragma unroll
        for (int r = 0; r < 4; ++r) {
            float p = 0.f;
#pragma unroll
            for (int j = 0; j < 8; ++j)
                p += vv[j] * tanh_fast(acc[i][j][r] + pe[j]);
            p += __shfl_xor(p, 1);
            p += __shfl_xor(p, 2);
            p += __shfl_xor(p, 4);
            p += __shfl_xor(p, 8);
            if (c == 0) red[w][i * 16 + qd * 4 + r] = p;
        }
    __syncthreads();
    if (tid < 64) {
        float raw = red[0][tid] + red[1][tid] + red[2][tid] + red[3][tid];
        wsal[btBase + tid] = raw;
        sv[tid] = (mask[btBase + tid] != 0) ? 1.f / (1.f + __expf(-raw)) : 0.f;
    }
    __syncthreads();
    // ---- epilogue 2: fused context partial for this block's 64 rows ----
    {
        float cacc[8];
#pragma unroll
        for (int k = 0; k < 8; ++k) cacc[k] = 0.f;
        const float* ar = annots + (size_t)(btBase + w * 16) * 512 + lane * 8;
#pragma unroll 4
        for (int r2 = 0; r2 < 16; ++r2) {
            float s = sv[w * 16 + r2];
            float4 va = *(const float4*)(ar + (size_t)r2 * 512);
            float4 vb = *(const float4*)(ar + (size_t)r2 * 512 + 4);
            cacc[0] += s * va.x; cacc[1] += s * va.y;
            cacc[2] += s * va.z; cacc[3] += s * va.w;
            cacc[4] += s * vb.x; cacc[5] += s * vb.y;
            cacc[6] += s * vb.z; cacc[7] += s * vb.w;
        }
        float* cxf = (float*)&Bs[0][0];
#pragma unroll
        for (int k = 0; k < 8; ++k) cxf[w * 512 + lane * 8 + k] = cacc[k];
        __syncthreads();
        const int chunk = blockIdx.x & 15;
        float* cp = ctxP + ((size_t)chunk * 64 + b) * 512;
        int d0 = tid * 2;
        cp[d0]     = cxf[d0]     + cxf[512 + d0]     + cxf[1024 + d0]     + cxf[1536 + d0];
        cp[d0 + 1] = cxf[d0 + 1] + cxf[512 + d0 + 1] + cxf[1024 + d0 + 1] + cxf[1536 + d0 + 1];
    }
}

// ---------- 5. normalize: alignment out + context reduce (16 chunks) ----------
__global__ __launch_bounds__(256) void k_ctxB(
    const float* __restrict__ wsal, const int* __restrict__ mask,
    const float* __restrict__ ctxP, float* __restrict__ out)
{
    __shared__ float sv[1024];
    __shared__ float wsum[4];
    const int b = blockIdx.x;
    const int tid = threadIdx.x;
    float lsum = 0.f;
#pragma unroll
    for (int p = 0; p < 4; ++p) {
        int t = p * 256 + tid;
        int bt = b * 1024 + t;
        float raw = wsal[bt];
        float s = (mask[bt] != 0) ? 1.f / (1.f + __expf(-raw)) : 0.f;
        sv[t] = s;
        lsum += s;
    }
    for (int off = 32; off > 0; off >>= 1) lsum += __shfl_xor(lsum, off);
    if ((tid & 63) == 0) wsum[tid >> 6] = lsum;
    __syncthreads();
    const float tot = wsum[0] + wsum[1] + wsum[2] + wsum[3];
    const float inv = 1.f / tot;
#pragma unroll
    for (int p = 0; p < 4; ++p) {
        int t = p * 256 + tid;
        out[98304 + b * 1024 + t] = sv[t] * inv;
    }
#pragma unroll
    for (int h = 0; h < 2; ++h) {
        int d = h * 256 + tid;
        float csum = 0.f;
#pragma unroll
        for (int tc = 0; tc < 16; ++tc)
            csum += ctxP[((size_t)tc * 64 + b) * 512 + d];
        out[65536 + b * 512 + d] = csum * inv;
    }
}

extern "C" void kernel_launch(void* const* d_in, const int* in_sizes, int n_in,
                              void* d_out, int out_size, void* d_ws, size_t ws_size,
                              hipStream_t stream) {
    const float* memory    = (const float*)d_in[0];
    const float* context   = (const float*)d_in[1];
    const float* rnn_state = (const float*)d_in[2];
    const float* annots    = (const float*)d_in[3];
    const float* atten     = (const float*)d_in[4];
    const int*   mask      = (const int*)d_in[5];
    const float* W_ih   = (const float*)d_in[7];
    const float* W_hh   = (const float*)d_in[8];
    const float* b_ih   = (const float*)d_in[9];
    const float* b_hh   = (const float*)d_in[10];
    const float* conv_w = (const float*)d_in[11];
    const float* loc_w  = (const float*)d_in[12];
    const float* loc_b  = (const float*)d_in[13];
    const float* q_w    = (const float*)d_in[14];
    const float* q_b    = (const float*)d_in[15];
    const float* a_w    = (const float*)d_in[16];
    const float* a_b    = (const float*)d_in[17];
    const float* v_w    = (const float*)d_in[18];
    float* out = (float*)d_out;

    char* w8 = (char*)d_ws;
    unsigned short* Lconv = (unsigned short*)(w8 + 0);         //  4,194,304
    unsigned short* Bbig  = (unsigned short*)(w8 + 4194304);   //    557,056
    unsigned short* Wihb  = (unsigned short*)(w8 + 4751360);   //  6,291,456
    unsigned short* Whhb  = (unsigned short*)(w8 + 11042816);  //  6,291,456
    unsigned short* qwb   = (unsigned short*)(w8 + 17334272);  //  1,048,576
    unsigned short* X1b   = (unsigned short*)(w8 + 18382848);  //    131,072
    unsigned short* X2b   = (unsigned short*)(w8 + 18513920);  //    131,072
    unsigned short* X3b   = (unsigned short*)(w8 + 18644992);  //    131,072
    float*          Cgru  = (float*)(w8 + 18776064);           //  3,145,728 (2 K-split partials)
    // pqP (8 partials, 1MB) aliases Cgru (dead after k_gates).
    // ctxP (16 x 64 x 512 f32 = 2MB) aliases Wihb (dead after GRU gemm).
    float*          pqP   = (float*)(w8 + 18776064);           //  1,048,576
    float*          ctxP  = (float*)(w8 + 4751360);            //  2,097,152
    float*          wsal  = (float*)(w8 + 19824640);           //    262,144
    float*          ebias = (float*)(w8 + 21921792);           //      2,048

    k_prep<<<NCVT + 512, 256, 0, stream>>>(W_ih, W_hh, q_w, rnn_state, memory, context,
                                           a_w, loc_w, a_b, loc_b, atten, conv_w,
                                           Wihb, Whhb, qwb, X2b, X1b, Bbig, ebias, Lconv);
    // GRU: N=6144 (gi|gh), 48 N-tiles x K-split2 = 96 blocks
    k_gemm_ks<<<96, 256, 0, stream>>>(X1b, X2b, Wihb, Whhb, Cgru, 6144, 48, 3072, 1024, 512);
    k_gates<<<256, 256, 0, stream>>>(Cgru, rnn_state, b_ih, b_hh, out, X3b);
    // pq: N=512, 4 N-tiles x K-split8 (Klen=128) = 32 blocks
    k_gemm_ks<<<32, 256, 0, stream>>>(X3b, X3b, qwb, qwb, pqP, 512, 4, 0x40000000, 1024, 128);
    k_attn<<<1024, 256, 0, stream>>>(annots, Lconv, Bbig, pqP, q_b, ebias, v_w, mask, wsal, ctxP);
    k_ctxB<<<64, 256, 0, stream>>>(wsal, mask, ctxP, out);
}